// Round 8
// baseline (299.912 us; speedup 1.0000x reference)
//
#include <hip/hip_runtime.h>
#include <hip/hip_bf16.h>
#include <math.h>

#define DIMSZ 1024
#define NHEAD 16
#define HDIM 64
#define BATCH 2
#define SEQ 2048
#define NROWS (BATCH * SEQ)   // 4096

// softmax in exp2 domain: fold 1/sqrt(64) * log2(e) into Q at conversion
#define QSCALE 0.18033688011112042592f

typedef __attribute__((ext_vector_type(8))) short bf16x8;
typedef __attribute__((ext_vector_type(4))) float f32x4;

__device__ __forceinline__ int swz(int m) { return (m ^ (m >> 2)) & 3; }

__device__ __forceinline__ unsigned hipack(unsigned a, unsigned b) {
    return __builtin_amdgcn_perm(b, a, 0x07060302u);
}

// truncation split: hi = trunc-bf16(x), lo = trunc-bf16(x - hi)
__device__ __forceinline__ void cvt2(float x, float y, unsigned& h, unsigned& l) {
    unsigned ux = __float_as_uint(x), uy = __float_as_uint(y);
    h = hipack(ux, uy);
    float rx = x - __uint_as_float(ux & 0xFFFF0000u);
    float ry = y - __uint_as_float(uy & 0xFFFF0000u);
    l = hipack(__float_as_uint(rx), __float_as_uint(ry));
}

__device__ __forceinline__ void cvt8(const float4& f0, const float4& f1,
                                     uint4& hv, uint4& lv) {
    cvt2(f0.x, f0.y, hv.x, lv.x);
    cvt2(f0.z, f0.w, hv.y, lv.y);
    cvt2(f1.x, f1.y, hv.z, lv.z);
    cvt2(f1.z, f1.w, hv.w, lv.w);
}

__device__ __forceinline__ ushort f2bf(float x) {
    union { __hip_bfloat16 b; ushort u; } cv;
    cv.b = __float2bfloat16(x);
    return cv.u;
}

__device__ __forceinline__ void gld16(const void* g, void* l) {
    __builtin_amdgcn_global_load_lds((const __attribute__((address_space(1))) void*)g,
                                     (__attribute__((address_space(3))) void*)l,
                                     16, 0, 0);
}

// ---------------------------------------------------------------------------
// Fused split-convert of all fp32 operands (x, Wq, Wk, Wv, Wo) in ONE launch.
// ---------------------------------------------------------------------------
__global__ __launch_bounds__(256) void convert_all(
    const float* __restrict__ x,
    const float* __restrict__ Wq, const float* __restrict__ Wk,
    const float* __restrict__ Wv, const float* __restrict__ Wo,
    ushort* __restrict__ Xhi, ushort* __restrict__ Xlo,
    ushort* __restrict__ Whi, ushort* __restrict__ Wlo,
    ushort* __restrict__ Wohi, ushort* __restrict__ Wolo)
{
    const int b = blockIdx.x;
    const float* src;
    ushort *hi, *lo;
    size_t off;
    if (b < 2048)      { src = x;  hi = Xhi;  lo = Xlo;  off = (size_t)b * 2048; }
    else if (b < 2560) { src = Wq; hi = Whi;             lo = Wlo;             off = (size_t)(b - 2048) * 2048; }
    else if (b < 3072) { src = Wk; hi = Whi + (1 << 20); lo = Wlo + (1 << 20); off = (size_t)(b - 2560) * 2048; }
    else if (b < 3584) { src = Wv; hi = Whi + 2 * (1 << 20); lo = Wlo + 2 * (1 << 20); off = (size_t)(b - 3072) * 2048; }
    else               { src = Wo; hi = Wohi; lo = Wolo; off = (size_t)(b - 3584) * 2048; }

    const size_t i = off + (size_t)threadIdx.x * 8;
    const float4 f0 = *(const float4*)&src[i];
    const float4 f1 = *(const float4*)&src[i + 4];
    uint4 hv, lv;
    cvt8(f0, f1, hv, lv);
    *(uint4*)&hi[i] = hv;
    *(uint4*)&lo[i] = lv;
}

// ---------------------------------------------------------------------------
// Fused QKV GEMM (split-bf16 MFMA).
// A-frags load DIRECT from global into registers (row-major layout == MFMA
// A-frag layout: lane lm = row, 16B at col lq*8; 4 lanes cover a full 64B
// line), prefetched one iter ahead. LDS holds only B (double-buffered gld16):
// per-iter LDS port traffic halves vs r7 (stage 16KB + read 32KB).
// ---------------------------------------------------------------------------
__global__ __launch_bounds__(256) void qkv_gemm(
    const ushort* __restrict__ Xhi, const ushort* __restrict__ Xlo,
    const ushort* __restrict__ Whi, const ushort* __restrict__ Wlo,
    const float* __restrict__ bq, const float* __restrict__ bk,
    const float* __restrict__ bv,
    ushort* __restrict__ Qb, ushort* __restrict__ Kb, ushort* __restrict__ Vt)
{
    // staging: [2][8192] (Bh[4096]+Bl[4096] per buf, 32KB); epilogue: 128x136
    __shared__ __align__(16) ushort smem[17408];

    const int tid = threadIdx.x;
    const int wave = tid >> 6;
    const int lane = tid & 63;
    const int lm = lane & 15;
    const int lq = lane >> 4;
    const int wy = wave >> 1;
    const int wx = wave & 1;
    const int m0 = blockIdx.x * 128;
    const int nbase = blockIdx.y * 128;

    // B staging map: thread t -> row r0 = t>>2 (and r0+64), slot c = t&3
    const int c = tid & 3;
    const int r0 = tid >> 2;
    const int g = c ^ swz(r0 & 15);
    const ushort* gbh = Whi + (size_t)(nbase + r0) * DIMSZ + g * 8;
    const ushort* gbl = Wlo + (size_t)(nbase + r0) * DIMSZ + g * 8;
    const int wofs = wave * 512;

    // A direct-load bases (per-lane): row m0 + wy*64 + i*16 + lm, col lq*8
    const ushort* gah = Xhi + (size_t)(m0 + wy * 64 + lm) * DIMSZ + lq * 8;
    const ushort* gal = Xlo + (size_t)(m0 + wy * 64 + lm) * DIMSZ + lq * 8;

    // B frag read offsets
    const int fo = lm * 32 + (((lq ^ swz(lm)) & 3) << 3);
    int bofs[4];
#pragma unroll
    for (int j = 0; j < 4; ++j) bofs[j] = (wx * 64 + j * 16) * 32 + fo;

    f32x4 acc[4][4] = {};

    // prologue: A0 frags -> regs; B0 -> buf0
    bf16x8 ah[4], al[4];
#pragma unroll
    for (int i = 0; i < 4; ++i) {
        ah[i] = *(const bf16x8*)(gah + i * 16 * DIMSZ);
        al[i] = *(const bf16x8*)(gal + i * 16 * DIMSZ);
    }
    gld16(gbh, smem + wofs);              gld16(gbh + 64 * DIMSZ, smem + 2048 + wofs);
    gld16(gbl, smem + 4096 + wofs);       gld16(gbl + 64 * DIMSZ, smem + 4096 + 2048 + wofs);

#pragma unroll 2
    for (int kk = 0; kk < 32; ++kk) {
        __syncthreads();   // B buf kk&1 staged; prev-iter A reg loads drained

        bf16x8 anh[4], anl[4];
        const bool more = (kk + 1 < 32);
        if (more) {
            const int k0 = (kk + 1) * 32;
#pragma unroll
            for (int i = 0; i < 4; ++i) {
                anh[i] = *(const bf16x8*)(gah + i * 16 * DIMSZ + k0);
                anl[i] = *(const bf16x8*)(gal + i * 16 * DIMSZ + k0);
            }
            ushort* nb = smem + ((kk + 1) & 1) * 8192;
            gld16(gbh + k0, nb + wofs);          gld16(gbh + 64 * DIMSZ + k0, nb + 2048 + wofs);
            gld16(gbl + k0, nb + 4096 + wofs);   gld16(gbl + 64 * DIMSZ + k0, nb + 4096 + 2048 + wofs);
        }

        const ushort* Bh = smem + (kk & 1) * 8192;
        const ushort* Bl = Bh + 4096;

        bf16x8 bhf[4], blf[4];
#pragma unroll
        for (int j = 0; j < 4; ++j) {
            bhf[j] = *(const bf16x8*)&Bh[bofs[j]];
            blf[j] = *(const bf16x8*)&Bl[bofs[j]];
        }
#pragma unroll
        for (int i = 0; i < 4; ++i)
#pragma unroll
            for (int j = 0; j < 4; ++j) {
                acc[i][j] = __builtin_amdgcn_mfma_f32_16x16x32_bf16(ah[i], bhf[j], acc[i][j], 0, 0, 0);
                acc[i][j] = __builtin_amdgcn_mfma_f32_16x16x32_bf16(ah[i], blf[j], acc[i][j], 0, 0, 0);
                acc[i][j] = __builtin_amdgcn_mfma_f32_16x16x32_bf16(al[i], bhf[j], acc[i][j], 0, 0, 0);
            }

        if (more) {
#pragma unroll
            for (int i = 0; i < 4; ++i) { ah[i] = anh[i]; al[i] = anl[i]; }
        }
    }

    const int mat = blockIdx.y >> 3;      // 0:Q 1:K 2:V (block-uniform)
    const float* bias = (mat == 0) ? bq : (mat == 1) ? bk : bv;
    const int nloc0 = (blockIdx.y & 7) * 128;
    const int b = m0 >> 11;
    const int s0 = m0 & (SEQ - 1);
    ushort* sf = smem;                    // flat reuse (17408 ushorts)

    __syncthreads();   // last B frag reads complete before smem reuse

    if (mat == 2) {
        // ---- V: transpose to [d][s], key-permuted within 32-blocks
#pragma unroll
        for (int j = 0; j < 4; ++j) {
            const int nc = nloc0 + wx * 64 + j * 16 + lm;
            const float bb = bias[nc];
            const int d = j * 16 + lm;
#pragma unroll
            for (int i = 0; i < 4; ++i) {
                // permuted position within 32-block: 8*lq + 4*(i&1) + rr
                const int ss = wy * 64 + (i >> 1) * 32 + lq * 8 + (i & 1) * 4;
                ushort4 pk;
                pk.x = f2bf(acc[i][j][0] + bb);
                pk.y = f2bf(acc[i][j][1] + bb);
                pk.z = f2bf(acc[i][j][2] + bb);
                pk.w = f2bf(acc[i][j][3] + bb);
                *(ushort4*)&sf[(wx * 64 + d) * 136 + ss] = pk;
            }
        }
        __syncthreads();
#pragma unroll
        for (int p = 0; p < 8; ++p) {
            const int idx = p * 256 + tid;
            const int row = idx >> 4;          // hh*64 + d
            const int hh = row >> 6;
            const int d = row & 63;
            const int sseg = (idx & 15) * 8;
            const uint4 v = *(const uint4*)&sf[row * 136 + sseg];
            const int hg = (nloc0 >> 6) + hh;
            *(uint4*)&Vt[((size_t)(b * NHEAD + hg) * HDIM + d) * SEQ + s0 + sseg] = v;
        }
    } else {
        // ---- Q/K: [s][d] tile in LDS, uint4 coalesced out
        ushort* dst = (mat == 0) ? Qb : Kb;
        const float sc = (mat == 0) ? QSCALE : 1.0f;
#pragma unroll
        for (int j = 0; j < 4; ++j) {
            const int col = wx * 64 + j * 16 + lm;      // 0..127
            const float bb = bias[nloc0 + col];
#pragma unroll
            for (int i = 0; i < 4; ++i) {
                const int rbase = wy * 64 + i * 16 + lq * 4;
#pragma unroll
                for (int rr = 0; rr < 4; ++rr)
                    sf[(rbase + rr) * 136 + col] = f2bf((acc[i][j][rr] + bb) * sc);
            }
        }
        __syncthreads();
#pragma unroll
        for (int p = 0; p < 8; ++p) {
            const int idx = p * 256 + tid;
            const int row = idx >> 4;          // local s: 0..127
            const int seg = idx & 15;          // 8-col segment
            const uint4 v = *(const uint4*)&sf[row * 136 + seg * 8];
            const int nc0 = nloc0 + seg * 8;
            const int h = nc0 >> 6;
            const int d = nc0 & 63;
            *(uint4*)&dst[((size_t)(b * NHEAD + h) * SEQ + s0 + row) * HDIM + d] = v;
        }
    }
}

// ---------------------------------------------------------------------------
// MFMA flash attention, S^T formulation (unchanged).
// ---------------------------------------------------------------------------
__global__ __launch_bounds__(256) void flash_attn_mfma(
    const ushort* __restrict__ Qb, const ushort* __restrict__ Kb,
    const ushort* __restrict__ Vt,
    ushort* __restrict__ CTXhi, ushort* __restrict__ CTXlo)
{
    __shared__ __align__(16) ushort Ks[2][4096];
    __shared__ __align__(16) ushort Vs[2][4096];

    const int tid = threadIdx.x;
    const int w = tid >> 6;
    const int l = tid & 63;
    const int lm = l & 15;
    const int lq = l >> 4;
    const int q0 = blockIdx.x * 128;
    const int bh = blockIdx.y;

    const ushort* Kg = Kb + (size_t)bh * SEQ * HDIM;
    const ushort* Vg = Vt + (size_t)bh * HDIM * SEQ;

    const int srow = w * 8 + (l >> 3);
    const int sc_ = (l & 7) ^ ((l >> 3) & 7);

    bf16x8 qf[2][2];
#pragma unroll
    for (int rt = 0; rt < 2; ++rt)
#pragma unroll
        for (int kt = 0; kt < 2; ++kt)
            qf[rt][kt] = *(const bf16x8*)&Qb[((size_t)bh * SEQ + q0 + w * 32 + rt * 16 + lm) * HDIM + kt * 32 + lq * 8];

    int koff[4][2];
#pragma unroll
    for (int t = 0; t < 4; ++t)
#pragma unroll
        for (int kt = 0; kt < 2; ++kt)
            koff[t][kt] = (t * 16 + lm) * 64 + (((kt * 4 + lq) ^ (lm & 7)) << 3);

    f32x4 o[2][4] = {};
    float l_[2] = {0.0f, 0.0f};

    {
        ushort* kb = &Ks[0][0];
        ushort* vb = &Vs[0][0];
#pragma unroll
        for (int p = 0; p < 2; ++p) {
            const int row = p * 32 + srow;
            gld16(Kg + (size_t)row * HDIM + sc_ * 8, kb + (p * 32 + w * 8) * 64);
            gld16(Vg + (size_t)row * SEQ + sc_ * 8, vb + (p * 32 + w * 8) * 64);
        }
    }

    for (int ch = 0; ch < SEQ / 64; ++ch) {
        __syncthreads();

        if (ch + 1 < SEQ / 64) {
            const int kc = (ch + 1) * 64;
            ushort* kb = &Ks[(ch + 1) & 1][0];
            ushort* vb = &Vs[(ch + 1) & 1][0];
#pragma unroll
            for (int p = 0; p < 2; ++p) {
                const int row = p * 32 + srow;
                gld16(Kg + (size_t)(kc + row) * HDIM + sc_ * 8, kb + (p * 32 + w * 8) * 64);
                gld16(Vg + (size_t)row * SEQ + kc + sc_ * 8, vb + (p * 32 + w * 8) * 64);
            }
        }

        const ushort* kb = &Ks[ch & 1][0];
        const ushort* vb = &Vs[ch & 1][0];

        f32x4 st[2][4] = {};
#pragma unroll
        for (int ct = 0; ct < 4; ++ct)
#pragma unroll
            for (int kt = 0; kt < 2; ++kt) {
                const bf16x8 kf = *(const bf16x8*)&kb[koff[ct][kt]];
#pragma unroll
                for (int rt = 0; rt < 2; ++rt)
                    st[rt][ct] = __builtin_amdgcn_mfma_f32_16x16x32_bf16(kf, qf[rt][kt], st[rt][ct], 0, 0, 0);
            }

#pragma unroll
        for (int rt = 0; rt < 2; ++rt) {
            float ls = 0.0f;
#pragma unroll
            for (int ct = 0; ct < 4; ++ct)
#pragma unroll
                for (int r = 0; r < 4; ++r) {
                    const float p = __builtin_amdgcn_exp2f(st[rt][ct][r]);
                    st[rt][ct][r] = p;
                    ls += p;
                }
            ls += __shfl_xor(ls, 16, 64);
            ls += __shfl_xor(ls, 32, 64);
            l_[rt] += ls;
        }

        bf16x8 pf[2][2];
#pragma unroll
        for (int rt = 0; rt < 2; ++rt)
#pragma unroll
            for (int kt2 = 0; kt2 < 2; ++kt2) {
                union { bf16x8 v; ushort u[8]; } pk;
#pragma unroll
                for (int t = 0; t < 2; ++t)
#pragma unroll
                    for (int r = 0; r < 4; ++r)
                        pk.u[t * 4 + r] = f2bf(st[rt][kt2 * 2 + t][r]);
                pf[rt][kt2] = pk.v;
            }

#pragma unroll
        for (int dt = 0; dt < 4; ++dt)
#pragma unroll
            for (int kt2 = 0; kt2 < 2; ++kt2) {
                const bf16x8 vf = *(const bf16x8*)&vb[koff[dt][kt2]];
#pragma unroll
                for (int rt = 0; rt < 2; ++rt)
                    o[rt][dt] = __builtin_amdgcn_mfma_f32_16x16x32_bf16(pf[rt][kt2], vf, o[rt][dt], 0, 0, 0);
            }
    }

    const int b = bh >> 4;
    const int h = bh & 15;
#pragma unroll
    for (int rt = 0; rt < 2; ++rt) {
        const float linv_me = 1.0f / l_[rt];
#pragma unroll
        for (int r = 0; r < 4; ++r) {
            const float lr = __shfl(linv_me, lq * 4 + r, 64);
            const int srow_ = q0 + w * 32 + rt * 16 + lq * 4 + r;
            const size_t base = ((size_t)b * SEQ + srow_) * DIMSZ + h * HDIM;
#pragma unroll
            for (int dt = 0; dt < 4; ++dt) {
                const float v = o[rt][dt][r] * lr;
                const unsigned uv = __float_as_uint(v);
                CTXhi[base + dt * 16 + lm] = (ushort)(uv >> 16);
                const float res = v - __uint_as_float(uv & 0xFFFF0000u);
                CTXlo[base + dt * 16 + lm] = (ushort)(__float_as_uint(res) >> 16);
            }
        }
    }
}

// ---------------------------------------------------------------------------
// Output projection: A-frags direct from global (register prefetch), B-only
// LDS double buffer. 64x128 tiles -> 512 blocks.
// ---------------------------------------------------------------------------
__global__ __launch_bounds__(256) void oproj_gemm(
    const ushort* __restrict__ Ahi_g, const ushort* __restrict__ Alo_g,
    const ushort* __restrict__ Bhi_g, const ushort* __restrict__ Blo_g,
    const float* __restrict__ bias, float* __restrict__ out)
{
    __shared__ __align__(16) ushort smem[2][8192];   // B only: 32KB

    const int tid = threadIdx.x;
    const int wave = tid >> 6;
    const int lane = tid & 63;
    const int lm = lane & 15;
    const int lq = lane >> 4;
    const int wy = wave >> 1;
    const int wx = wave & 1;
    const int m0 = blockIdx.x * 64;
    const int n0 = blockIdx.y * 128;

    const int c = tid & 3;
    const int r0 = tid >> 2;
    const int g = c ^ swz(r0 & 15);
    const ushort* gbh = Bhi_g + (size_t)(n0 + r0) * DIMSZ + g * 8;
    const ushort* gbl = Blo_g + (size_t)(n0 + r0) * DIMSZ + g * 8;
    const int wofs = wave * 512;

    const ushort* gah = Ahi_g + (size_t)(m0 + wy * 32 + lm) * DIMSZ + lq * 8;
    const ushort* gal = Alo_g + (size_t)(m0 + wy * 32 + lm) * DIMSZ + lq * 8;

    const int fo = lm * 32 + (((lq ^ swz(lm)) & 3) << 3);
    int bofs[4];
#pragma unroll
    for (int j = 0; j < 4; ++j) bofs[j] = (wx * 64 + j * 16) * 32 + fo;

    f32x4 acc[2][4] = {};

    bf16x8 ah[2], al[2];
#pragma unroll
    for (int i = 0; i < 2; ++i) {
        ah[i] = *(const bf16x8*)(gah + i * 16 * DIMSZ);
        al[i] = *(const bf16x8*)(gal + i * 16 * DIMSZ);
    }
    {
        ushort* b0 = &smem[0][0];
        gld16(gbh, b0 + wofs);            gld16(gbh + 64 * DIMSZ, b0 + 2048 + wofs);
        gld16(gbl, b0 + 4096 + wofs);     gld16(gbl + 64 * DIMSZ, b0 + 4096 + 2048 + wofs);
    }

#pragma unroll 2
    for (int kk = 0; kk < 32; ++kk) {
        __syncthreads();

        bf16x8 anh[2], anl[2];
        const bool more = (kk + 1 < 32);
        if (more) {
            const int k0 = (kk + 1) * 32;
#pragma unroll
            for (int i = 0; i < 2; ++i) {
                anh[i] = *(const bf16x8*)(gah + i * 16 * DIMSZ + k0);
                anl[i] = *(const bf16x8*)(gal + i * 16 * DIMSZ + k0);
            }
            ushort* nb = &smem[(kk + 1) & 1][0];
            gld16(gbh + k0, nb + wofs);          gld16(gbh + 64 * DIMSZ + k0, nb + 2048 + wofs);
            gld16(gbl + k0, nb + 4096 + wofs);   gld16(gbl + 64 * DIMSZ + k0, nb + 4096 + 2048 + wofs);
        }

        const ushort* Bh = &smem[kk & 1][0];
        const ushort* Bl = Bh + 4096;

        bf16x8 bhf[4], blf[4];
#pragma unroll
        for (int j = 0; j < 4; ++j) {
            bhf[j] = *(const bf16x8*)&Bh[bofs[j]];
            blf[j] = *(const bf16x8*)&Bl[bofs[j]];
        }
#pragma unroll
        for (int i = 0; i < 2; ++i)
#pragma unroll
            for (int j = 0; j < 4; ++j) {
                acc[i][j] = __builtin_amdgcn_mfma_f32_16x16x32_bf16(ah[i], bhf[j], acc[i][j], 0, 0, 0);
                acc[i][j] = __builtin_amdgcn_mfma_f32_16x16x32_bf16(ah[i], blf[j], acc[i][j], 0, 0, 0);
                acc[i][j] = __builtin_amdgcn_mfma_f32_16x16x32_bf16(al[i], bhf[j], acc[i][j], 0, 0, 0);
            }

        if (more) {
#pragma unroll
            for (int i = 0; i < 2; ++i) { ah[i] = anh[i]; al[i] = anl[i]; }
        }
    }

#pragma unroll
    for (int j = 0; j < 4; ++j) {
        const int nc = n0 + wx * 64 + j * 16 + lm;
        const float bb = bias[nc];
#pragma unroll
        for (int i = 0; i < 2; ++i) {
            const int mb = m0 + wy * 32 + i * 16 + lq * 4;
#pragma unroll
            for (int rr = 0; rr < 4; ++rr)
                out[(size_t)(mb + rr) * DIMSZ + nc] = acc[i][j][rr] + bb;
        }
    }
}

// ---------------------------------------------------------------------------
extern "C" void kernel_launch(void* const* d_in, const int* in_sizes, int n_in,
                              void* d_out, int out_size, void* d_ws, size_t ws_size,
                              hipStream_t stream)
{
    const float* x  = (const float*)d_in[0];
    const float* Wq = (const float*)d_in[1];
    const float* bq = (const float*)d_in[2];
    const float* Wk = (const float*)d_in[3];
    const float* bk = (const float*)d_in[4];
    const float* Wv = (const float*)d_in[5];
    const float* bv = (const float*)d_in[6];
    const float* Wo = (const float*)d_in[7];
    const float* bo = (const float*)d_in[8];
    float* out = (float*)d_out;

    const size_t elems = (size_t)NROWS * DIMSZ;   // 4M
    ushort* Qb    = (ushort*)d_ws;                // 8MB
    ushort* Kb    = Qb + elems;                   // 8MB
    ushort* Vt    = Kb + elems;                   // 8MB
    ushort* CTXhi = Vt + elems;                   // 8MB  (overlay: Xhi)
    ushort* CTXlo = CTXhi + elems;                // 8MB  (overlay: Xlo)
    ushort* Whi   = CTXlo + elems;                // 6MB
    ushort* Wlo   = Whi + 3 * (1 << 20);          // 6MB
    ushort* Wohi  = Wlo + 3 * (1 << 20);          // 2MB
    ushort* Wolo  = Wohi + (1 << 20);             // 2MB  (peak 56MB)
    ushort* Xhi   = CTXhi;                        // dead before flash writes CTX
    ushort* Xlo   = CTXlo;

    convert_all<<<4096, 256, 0, stream>>>(x, Wq, Wk, Wv, Wo,
                                          Xhi, Xlo, Whi, Wlo, Wohi, Wolo);

    qkv_gemm<<<dim3(32, 24), 256, 0, stream>>>(Xhi, Xlo, Whi, Wlo, bq, bk, bv, Qb, Kb, Vt);

    flash_attn_mfma<<<dim3(SEQ / 128, BATCH * NHEAD), 256, 0, stream>>>(Qb, Kb, Vt, CTXhi, CTXlo);

    oproj_gemm<<<dim3(64, 8), 256, 0, stream>>>(CTXhi, CTXlo, Wohi, Wolo, bo, out);
}

// Round 9
// 243.978 us; speedup vs baseline: 1.2293x; 1.2293x over previous
//
#include <hip/hip_runtime.h>
#include <hip/hip_bf16.h>
#include <math.h>

#define DIMSZ 1024
#define NHEAD 16
#define HDIM 64
#define BATCH 2
#define SEQ 2048
#define NROWS (BATCH * SEQ)   // 4096

// softmax in exp2 domain: fold 1/sqrt(64) * log2(e) into Q at conversion
#define QSCALE 0.18033688011112042592f

typedef __attribute__((ext_vector_type(8))) short bf16x8;
typedef __attribute__((ext_vector_type(4))) float f32x4;

__device__ __forceinline__ int swz(int m) { return (m ^ (m >> 2)) & 3; }

__device__ __forceinline__ unsigned hipack(unsigned a, unsigned b) {
    return __builtin_amdgcn_perm(b, a, 0x07060302u);
}

// truncation split: hi = trunc-bf16(x), lo = trunc-bf16(x - hi)
__device__ __forceinline__ void cvt2(float x, float y, unsigned& h, unsigned& l) {
    unsigned ux = __float_as_uint(x), uy = __float_as_uint(y);
    h = hipack(ux, uy);
    float rx = x - __uint_as_float(ux & 0xFFFF0000u);
    float ry = y - __uint_as_float(uy & 0xFFFF0000u);
    l = hipack(__float_as_uint(rx), __float_as_uint(ry));
}

__device__ __forceinline__ void cvt8(const float4& f0, const float4& f1,
                                     uint4& hv, uint4& lv) {
    cvt2(f0.x, f0.y, hv.x, lv.x);
    cvt2(f0.z, f0.w, hv.y, lv.y);
    cvt2(f1.x, f1.y, hv.z, lv.z);
    cvt2(f1.z, f1.w, hv.w, lv.w);
}

__device__ __forceinline__ ushort f2bf(float x) {
    union { __hip_bfloat16 b; ushort u; } cv;
    cv.b = __float2bfloat16(x);
    return cv.u;
}

__device__ __forceinline__ void gld16(const void* g, void* l) {
    __builtin_amdgcn_global_load_lds((const __attribute__((address_space(1))) void*)g,
                                     (__attribute__((address_space(3))) void*)l,
                                     16, 0, 0);
}

// ---------------------------------------------------------------------------
// Fused split-convert of all fp32 operands (x, Wq, Wk, Wv, Wo) in ONE launch.
// ---------------------------------------------------------------------------
__global__ __launch_bounds__(256) void convert_all(
    const float* __restrict__ x,
    const float* __restrict__ Wq, const float* __restrict__ Wk,
    const float* __restrict__ Wv, const float* __restrict__ Wo,
    ushort* __restrict__ Xhi, ushort* __restrict__ Xlo,
    ushort* __restrict__ Whi, ushort* __restrict__ Wlo,
    ushort* __restrict__ Wohi, ushort* __restrict__ Wolo)
{
    const int b = blockIdx.x;
    const float* src;
    ushort *hi, *lo;
    size_t off;
    if (b < 2048)      { src = x;  hi = Xhi;  lo = Xlo;  off = (size_t)b * 2048; }
    else if (b < 2560) { src = Wq; hi = Whi;             lo = Wlo;             off = (size_t)(b - 2048) * 2048; }
    else if (b < 3072) { src = Wk; hi = Whi + (1 << 20); lo = Wlo + (1 << 20); off = (size_t)(b - 2560) * 2048; }
    else if (b < 3584) { src = Wv; hi = Whi + 2 * (1 << 20); lo = Wlo + 2 * (1 << 20); off = (size_t)(b - 3072) * 2048; }
    else               { src = Wo; hi = Wohi; lo = Wolo; off = (size_t)(b - 3584) * 2048; }

    const size_t i = off + (size_t)threadIdx.x * 8;
    const float4 f0 = *(const float4*)&src[i];
    const float4 f1 = *(const float4*)&src[i + 4];
    uint4 hv, lv;
    cvt8(f0, f1, hv, lv);
    *(uint4*)&hi[i] = hv;
    *(uint4*)&lo[i] = lv;
}

// ---------------------------------------------------------------------------
// Fused QKV GEMM (split-bf16 MFMA), SINGLE-buffered pure-gld16 staging
// (32KB LDS -> 3 blocks/CU, grid 768 fully resident, no dispatch tail).
// Two-phase barrier per iter: barrier1 = staging landed; ds_read frags;
// barrier2 = reads done (cheap: lgkm only, no vmem outstanding); then issue
// all 8 gld16 for tile k+1 with the MFMA block as flight time. Unlike r6's
// failed 2-barrier variant there are NO in-loop ds_writes / VALU converts.
// ---------------------------------------------------------------------------
__global__ __launch_bounds__(256, 3) void qkv_gemm(
    const ushort* __restrict__ Xhi, const ushort* __restrict__ Xlo,
    const ushort* __restrict__ Whi, const ushort* __restrict__ Wlo,
    const float* __restrict__ bq, const float* __restrict__ bk,
    const float* __restrict__ bv,
    ushort* __restrict__ Qb, ushort* __restrict__ Kb, ushort* __restrict__ Vt)
{
    // K-loop: Ah[0..4095] Al[..8191] Bh[..12287] Bl[..16383] (32KB)
    // epilogue reuse: 128 x 136 tile (17408 ushorts)
    __shared__ __align__(16) ushort smem[17408];

    const int tid = threadIdx.x;
    const int wave = tid >> 6;
    const int lane = tid & 63;
    const int lm = lane & 15;
    const int lq = lane >> 4;
    const int wy = wave >> 1;
    const int wx = wave & 1;
    const int m0 = blockIdx.x * 128;
    const int nbase = blockIdx.y * 128;

    // staging map: thread t -> row r0 = t>>2 (and r0+64), LDS slot c = t&3,
    // global chunk g = c ^ swz(r0&15)
    const int c = tid & 3;
    const int r0 = tid >> 2;
    const int g = c ^ swz(r0 & 15);
    const ushort* gah = Xhi + (size_t)(m0 + r0) * DIMSZ + g * 8;
    const ushort* gal = Xlo + (size_t)(m0 + r0) * DIMSZ + g * 8;
    const ushort* gbh = Whi + (size_t)(nbase + r0) * DIMSZ + g * 8;
    const ushort* gbl = Wlo + (size_t)(nbase + r0) * DIMSZ + g * 8;
    const int wofs = wave * 512;

    // frag read offsets
    const int fo = lm * 32 + (((lq ^ swz(lm)) & 3) << 3);
    int aofs[4], bofs[4];
#pragma unroll
    for (int i = 0; i < 4; ++i) {
        aofs[i] = (wy * 64 + i * 16) * 32 + fo;
        bofs[i] = (wx * 64 + i * 16) * 32 + fo;
    }

    f32x4 acc[4][4] = {};

    // stage k-tile 0
    {
        gld16(gah, smem + wofs);                 gld16(gah + 64 * DIMSZ, smem + 2048 + wofs);
        gld16(gal, smem + 4096 + wofs);          gld16(gal + 64 * DIMSZ, smem + 6144 + wofs);
        gld16(gbh, smem + 8192 + wofs);          gld16(gbh + 64 * DIMSZ, smem + 10240 + wofs);
        gld16(gbl, smem + 12288 + wofs);         gld16(gbl + 64 * DIMSZ, smem + 14336 + wofs);
    }

    for (int kk = 0; kk < 32; ++kk) {
        __syncthreads();   // barrier1: staging for tile kk landed (vmcnt drain)

        const ushort* Ah = smem;
        const ushort* Al = smem + 4096;
        const ushort* Bh = smem + 8192;
        const ushort* Bl = smem + 12288;

        bf16x8 ahf[4], alf[4], bhf[4], blf[4];
#pragma unroll
        for (int i = 0; i < 4; ++i) {
            ahf[i] = *(const bf16x8*)&Ah[aofs[i]];
            alf[i] = *(const bf16x8*)&Al[aofs[i]];
            bhf[i] = *(const bf16x8*)&Bh[bofs[i]];
            blf[i] = *(const bf16x8*)&Bl[bofs[i]];
        }

        __syncthreads();   // barrier2: all frag reads done (lgkm only — cheap)

        if (kk + 1 < 32) {
            const int k0 = (kk + 1) * 32;
            gld16(gah + k0, smem + wofs);                 gld16(gah + 64 * DIMSZ + k0, smem + 2048 + wofs);
            gld16(gal + k0, smem + 4096 + wofs);          gld16(gal + 64 * DIMSZ + k0, smem + 6144 + wofs);
            gld16(gbh + k0, smem + 8192 + wofs);          gld16(gbh + 64 * DIMSZ + k0, smem + 10240 + wofs);
            gld16(gbl + k0, smem + 12288 + wofs);         gld16(gbl + 64 * DIMSZ + k0, smem + 14336 + wofs);
        }

#pragma unroll
        for (int i = 0; i < 4; ++i)
#pragma unroll
            for (int j = 0; j < 4; ++j) {
                acc[i][j] = __builtin_amdgcn_mfma_f32_16x16x32_bf16(ahf[i], bhf[j], acc[i][j], 0, 0, 0);
                acc[i][j] = __builtin_amdgcn_mfma_f32_16x16x32_bf16(ahf[i], blf[j], acc[i][j], 0, 0, 0);
                acc[i][j] = __builtin_amdgcn_mfma_f32_16x16x32_bf16(alf[i], bhf[j], acc[i][j], 0, 0, 0);
            }
    }

    const int mat = blockIdx.y >> 3;      // 0:Q 1:K 2:V (block-uniform)
    const float* bias = (mat == 0) ? bq : (mat == 1) ? bk : bv;
    const int nloc0 = (blockIdx.y & 7) * 128;
    const int b = m0 >> 11;
    const int s0 = m0 & (SEQ - 1);
    ushort* sf = smem;                    // flat reuse (17408 ushorts)

    __syncthreads();   // K-loop traffic complete before smem reuse

    if (mat == 2) {
        // ---- V: transpose to [d][s], key-permuted within 32-blocks
#pragma unroll
        for (int j = 0; j < 4; ++j) {
            const int nc = nloc0 + wx * 64 + j * 16 + lm;
            const float bb = bias[nc];
            const int d = j * 16 + lm;
#pragma unroll
            for (int i = 0; i < 4; ++i) {
                // permuted position within 32-block: 8*lq + 4*(i&1) + rr
                const int ss = wy * 64 + (i >> 1) * 32 + lq * 8 + (i & 1) * 4;
                ushort4 pk;
                pk.x = f2bf(acc[i][j][0] + bb);
                pk.y = f2bf(acc[i][j][1] + bb);
                pk.z = f2bf(acc[i][j][2] + bb);
                pk.w = f2bf(acc[i][j][3] + bb);
                *(ushort4*)&sf[(wx * 64 + d) * 136 + ss] = pk;
            }
        }
        __syncthreads();
#pragma unroll
        for (int p = 0; p < 8; ++p) {
            const int idx = p * 256 + tid;
            const int row = idx >> 4;          // hh*64 + d
            const int hh = row >> 6;
            const int d = row & 63;
            const int sseg = (idx & 15) * 8;
            const uint4 v = *(const uint4*)&sf[row * 136 + sseg];
            const int hg = (nloc0 >> 6) + hh;
            *(uint4*)&Vt[((size_t)(b * NHEAD + hg) * HDIM + d) * SEQ + s0 + sseg] = v;
        }
    } else {
        // ---- Q/K: [s][d] tile in LDS, uint4 coalesced out
        ushort* dst = (mat == 0) ? Qb : Kb;
        const float sc = (mat == 0) ? QSCALE : 1.0f;
#pragma unroll
        for (int j = 0; j < 4; ++j) {
            const int col = wx * 64 + j * 16 + lm;      // 0..127
            const float bb = bias[nloc0 + col];
#pragma unroll
            for (int i = 0; i < 4; ++i) {
                const int rbase = wy * 64 + i * 16 + lq * 4;
#pragma unroll
                for (int rr = 0; rr < 4; ++rr)
                    sf[(rbase + rr) * 136 + col] = f2bf((acc[i][j][rr] + bb) * sc);
            }
        }
        __syncthreads();
#pragma unroll
        for (int p = 0; p < 8; ++p) {
            const int idx = p * 256 + tid;
            const int row = idx >> 4;          // local s: 0..127
            const int seg = idx & 15;          // 8-col segment
            const uint4 v = *(const uint4*)&sf[row * 136 + seg * 8];
            const int nc0 = nloc0 + seg * 8;
            const int h = nc0 >> 6;
            const int d = nc0 & 63;
            *(uint4*)&dst[((size_t)(b * NHEAD + h) * SEQ + s0 + row) * HDIM + d] = v;
        }
    }
}

// ---------------------------------------------------------------------------
// MFMA flash attention, S^T formulation (unchanged from r7).
// ---------------------------------------------------------------------------
__global__ __launch_bounds__(256) void flash_attn_mfma(
    const ushort* __restrict__ Qb, const ushort* __restrict__ Kb,
    const ushort* __restrict__ Vt,
    ushort* __restrict__ CTXhi, ushort* __restrict__ CTXlo)
{
    __shared__ __align__(16) ushort Ks[2][4096];
    __shared__ __align__(16) ushort Vs[2][4096];

    const int tid = threadIdx.x;
    const int w = tid >> 6;
    const int l = tid & 63;
    const int lm = l & 15;
    const int lq = l >> 4;
    const int q0 = blockIdx.x * 128;
    const int bh = blockIdx.y;

    const ushort* Kg = Kb + (size_t)bh * SEQ * HDIM;
    const ushort* Vg = Vt + (size_t)bh * HDIM * SEQ;

    const int srow = w * 8 + (l >> 3);
    const int sc_ = (l & 7) ^ ((l >> 3) & 7);

    bf16x8 qf[2][2];
#pragma unroll
    for (int rt = 0; rt < 2; ++rt)
#pragma unroll
        for (int kt = 0; kt < 2; ++kt)
            qf[rt][kt] = *(const bf16x8*)&Qb[((size_t)bh * SEQ + q0 + w * 32 + rt * 16 + lm) * HDIM + kt * 32 + lq * 8];

    int koff[4][2];
#pragma unroll
    for (int t = 0; t < 4; ++t)
#pragma unroll
        for (int kt = 0; kt < 2; ++kt)
            koff[t][kt] = (t * 16 + lm) * 64 + (((kt * 4 + lq) ^ (lm & 7)) << 3);

    f32x4 o[2][4] = {};
    float l_[2] = {0.0f, 0.0f};

    {
        ushort* kb = &Ks[0][0];
        ushort* vb = &Vs[0][0];
#pragma unroll
        for (int p = 0; p < 2; ++p) {
            const int row = p * 32 + srow;
            gld16(Kg + (size_t)row * HDIM + sc_ * 8, kb + (p * 32 + w * 8) * 64);
            gld16(Vg + (size_t)row * SEQ + sc_ * 8, vb + (p * 32 + w * 8) * 64);
        }
    }

    for (int ch = 0; ch < SEQ / 64; ++ch) {
        __syncthreads();

        if (ch + 1 < SEQ / 64) {
            const int kc = (ch + 1) * 64;
            ushort* kb = &Ks[(ch + 1) & 1][0];
            ushort* vb = &Vs[(ch + 1) & 1][0];
#pragma unroll
            for (int p = 0; p < 2; ++p) {
                const int row = p * 32 + srow;
                gld16(Kg + (size_t)(kc + row) * HDIM + sc_ * 8, kb + (p * 32 + w * 8) * 64);
                gld16(Vg + (size_t)row * SEQ + kc + sc_ * 8, vb + (p * 32 + w * 8) * 64);
            }
        }

        const ushort* kb = &Ks[ch & 1][0];
        const ushort* vb = &Vs[ch & 1][0];

        f32x4 st[2][4] = {};
#pragma unroll
        for (int ct = 0; ct < 4; ++ct)
#pragma unroll
            for (int kt = 0; kt < 2; ++kt) {
                const bf16x8 kf = *(const bf16x8*)&kb[koff[ct][kt]];
#pragma unroll
                for (int rt = 0; rt < 2; ++rt)
                    st[rt][ct] = __builtin_amdgcn_mfma_f32_16x16x32_bf16(kf, qf[rt][kt], st[rt][ct], 0, 0, 0);
            }

#pragma unroll
        for (int rt = 0; rt < 2; ++rt) {
            float ls = 0.0f;
#pragma unroll
            for (int ct = 0; ct < 4; ++ct)
#pragma unroll
                for (int r = 0; r < 4; ++r) {
                    const float p = __builtin_amdgcn_exp2f(st[rt][ct][r]);
                    st[rt][ct][r] = p;
                    ls += p;
                }
            ls += __shfl_xor(ls, 16, 64);
            ls += __shfl_xor(ls, 32, 64);
            l_[rt] += ls;
        }

        bf16x8 pf[2][2];
#pragma unroll
        for (int rt = 0; rt < 2; ++rt)
#pragma unroll
            for (int kt2 = 0; kt2 < 2; ++kt2) {
                union { bf16x8 v; ushort u[8]; } pk;
#pragma unroll
                for (int t = 0; t < 2; ++t)
#pragma unroll
                    for (int r = 0; r < 4; ++r)
                        pk.u[t * 4 + r] = f2bf(st[rt][kt2 * 2 + t][r]);
                pf[rt][kt2] = pk.v;
            }

#pragma unroll
        for (int dt = 0; dt < 4; ++dt)
#pragma unroll
            for (int kt2 = 0; kt2 < 2; ++kt2) {
                const bf16x8 vf = *(const bf16x8*)&vb[koff[dt][kt2]];
#pragma unroll
                for (int rt = 0; rt < 2; ++rt)
                    o[rt][dt] = __builtin_amdgcn_mfma_f32_16x16x32_bf16(pf[rt][kt2], vf, o[rt][dt], 0, 0, 0);
            }
    }

    const int b = bh >> 4;
    const int h = bh & 15;
#pragma unroll
    for (int rt = 0; rt < 2; ++rt) {
        const float linv_me = 1.0f / l_[rt];
#pragma unroll
        for (int r = 0; r < 4; ++r) {
            const float lr = __shfl(linv_me, lq * 4 + r, 64);
            const int srow_ = q0 + w * 32 + rt * 16 + lq * 4 + r;
            const size_t base = ((size_t)b * SEQ + srow_) * DIMSZ + h * HDIM;
#pragma unroll
            for (int dt = 0; dt < 4; ++dt) {
                const float v = o[rt][dt][r] * lr;
                const unsigned uv = __float_as_uint(v);
                CTXhi[base + dt * 16 + lm] = (ushort)(uv >> 16);
                const float res = v - __uint_as_float(uv & 0xFFFF0000u);
                CTXlo[base + dt * 16 + lm] = (ushort)(__float_as_uint(res) >> 16);
            }
        }
    }
}

// ---------------------------------------------------------------------------
// Output projection: pre-split bf16 operands, pure-gld16 double-buffered
// (exact r7 version: 48KB LDS, 512 blocks).
// ---------------------------------------------------------------------------
__global__ __launch_bounds__(256) void oproj_gemm(
    const ushort* __restrict__ Ahi_g, const ushort* __restrict__ Alo_g,
    const ushort* __restrict__ Bhi_g, const ushort* __restrict__ Blo_g,
    const float* __restrict__ bias, float* __restrict__ out)
{
    __shared__ __align__(16) ushort smem[2][12288];

    const int tid = threadIdx.x;
    const int wave = tid >> 6;
    const int lane = tid & 63;
    const int lm = lane & 15;
    const int lq = lane >> 4;
    const int wy = wave >> 1;
    const int wx = wave & 1;
    const int m0 = blockIdx.x * 64;
    const int n0 = blockIdx.y * 128;

    const int c = tid & 3;
    const int r0 = tid >> 2;
    const int g = c ^ swz(r0 & 15);
    const ushort* gah = Ahi_g + (size_t)(m0 + r0) * DIMSZ + g * 8;
    const ushort* gal = Alo_g + (size_t)(m0 + r0) * DIMSZ + g * 8;
    const ushort* gbh = Bhi_g + (size_t)(n0 + r0) * DIMSZ + g * 8;
    const ushort* gbl = Blo_g + (size_t)(n0 + r0) * DIMSZ + g * 8;
    const int wofs = wave * 512;

    const int fo = lm * 32 + (((lq ^ swz(lm)) & 3) << 3);
    int aofs[2], bofs[4];
#pragma unroll
    for (int i = 0; i < 2; ++i) aofs[i] = (wy * 32 + i * 16) * 32 + fo;
#pragma unroll
    for (int j = 0; j < 4; ++j) bofs[j] = (wx * 64 + j * 16) * 32 + fo;

    f32x4 acc[2][4] = {};

    {
        ushort* b0 = &smem[0][0];
        gld16(gah, b0 + wofs);
        gld16(gal, b0 + 2048 + wofs);
        gld16(gbh, b0 + 4096 + wofs);   gld16(gbh + 64 * DIMSZ, b0 + 4096 + 2048 + wofs);
        gld16(gbl, b0 + 8192 + wofs);   gld16(gbl + 64 * DIMSZ, b0 + 8192 + 2048 + wofs);
    }

    for (int kk = 0; kk < 32; ++kk) {
        __syncthreads();

        if (kk + 1 < 32) {
            const int k0 = (kk + 1) * 32;
            ushort* nb = &smem[(kk + 1) & 1][0];
            gld16(gah + k0, nb + wofs);
            gld16(gal + k0, nb + 2048 + wofs);
            gld16(gbh + k0, nb + 4096 + wofs);   gld16(gbh + 64 * DIMSZ + k0, nb + 4096 + 2048 + wofs);
            gld16(gbl + k0, nb + 8192 + wofs);   gld16(gbl + 64 * DIMSZ + k0, nb + 8192 + 2048 + wofs);
        }

        const ushort* Ah = &smem[kk & 1][0];
        const ushort* Al = Ah + 2048;
        const ushort* Bh = Ah + 4096;
        const ushort* Bl = Ah + 8192;

        bf16x8 ahf[2], alf[2], bhf[4], blf[4];
#pragma unroll
        for (int i = 0; i < 2; ++i) {
            ahf[i] = *(const bf16x8*)&Ah[aofs[i]];
            alf[i] = *(const bf16x8*)&Al[aofs[i]];
        }
#pragma unroll
        for (int j = 0; j < 4; ++j) {
            bhf[j] = *(const bf16x8*)&Bh[bofs[j]];
            blf[j] = *(const bf16x8*)&Bl[bofs[j]];
        }
#pragma unroll
        for (int i = 0; i < 2; ++i)
#pragma unroll
            for (int j = 0; j < 4; ++j) {
                acc[i][j] = __builtin_amdgcn_mfma_f32_16x16x32_bf16(ahf[i], bhf[j], acc[i][j], 0, 0, 0);
                acc[i][j] = __builtin_amdgcn_mfma_f32_16x16x32_bf16(ahf[i], blf[j], acc[i][j], 0, 0, 0);
                acc[i][j] = __builtin_amdgcn_mfma_f32_16x16x32_bf16(alf[i], bhf[j], acc[i][j], 0, 0, 0);
            }
    }

#pragma unroll
    for (int j = 0; j < 4; ++j) {
        const int nc = n0 + wx * 64 + j * 16 + lm;
        const float bb = bias[nc];
#pragma unroll
        for (int i = 0; i < 2; ++i) {
            const int mb = m0 + wy * 32 + i * 16 + lq * 4;
#pragma unroll
            for (int rr = 0; rr < 4; ++rr)
                out[(size_t)(mb + rr) * DIMSZ + nc] = acc[i][j][rr] + bb;
        }
    }
}

// ---------------------------------------------------------------------------
extern "C" void kernel_launch(void* const* d_in, const int* in_sizes, int n_in,
                              void* d_out, int out_size, void* d_ws, size_t ws_size,
                              hipStream_t stream)
{
    const float* x  = (const float*)d_in[0];
    const float* Wq = (const float*)d_in[1];
    const float* bq = (const float*)d_in[2];
    const float* Wk = (const float*)d_in[3];
    const float* bk = (const float*)d_in[4];
    const float* Wv = (const float*)d_in[5];
    const float* bv = (const float*)d_in[6];
    const float* Wo = (const float*)d_in[7];
    const float* bo = (const float*)d_in[8];
    float* out = (float*)d_out;

    const size_t elems = (size_t)NROWS * DIMSZ;   // 4M
    ushort* Qb    = (ushort*)d_ws;                // 8MB
    ushort* Kb    = Qb + elems;                   // 8MB
    ushort* Vt    = Kb + elems;                   // 8MB
    ushort* CTXhi = Vt + elems;                   // 8MB  (overlay: Xhi)
    ushort* CTXlo = CTXhi + elems;                // 8MB  (overlay: Xlo)
    ushort* Whi   = CTXlo + elems;                // 6MB
    ushort* Wlo   = Whi + 3 * (1 << 20);          // 6MB
    ushort* Wohi  = Wlo + 3 * (1 << 20);          // 2MB
    ushort* Wolo  = Wohi + (1 << 20);             // 2MB  (peak 56MB)
    ushort* Xhi   = CTXhi;                        // dead before flash writes CTX
    ushort* Xlo   = CTXlo;

    convert_all<<<4096, 256, 0, stream>>>(x, Wq, Wk, Wv, Wo,
                                          Xhi, Xlo, Whi, Wlo, Wohi, Wolo);

    qkv_gemm<<<dim3(32, 24), 256, 0, stream>>>(Xhi, Xlo, Whi, Wlo, bq, bk, bv, Qb, Kb, Vt);

    flash_attn_mfma<<<dim3(SEQ / 128, BATCH * NHEAD), 256, 0, stream>>>(Qb, Kb, Vt, CTXhi, CTXlo);

    oproj_gemm<<<dim3(64, 8), 256, 0, stream>>>(CTXhi, CTXlo, Wohi, Wolo, bo, out);
}

// Round 10
// 211.938 us; speedup vs baseline: 1.4151x; 1.1512x over previous
//
#include <hip/hip_runtime.h>
#include <hip/hip_bf16.h>
#include <math.h>

#define DIMSZ 1024
#define NHEAD 16
#define HDIM 64
#define BATCH 2
#define SEQ 2048
#define NROWS (BATCH * SEQ)   // 4096

// softmax in exp2 domain: fold 1/sqrt(64) * log2(e) into Q at conversion
#define QSCALE 0.18033688011112042592f

typedef __attribute__((ext_vector_type(8))) short bf16x8;
typedef __attribute__((ext_vector_type(4))) float f32x4;

__device__ __forceinline__ int swz(int m) { return (m ^ (m >> 2)) & 3; }

__device__ __forceinline__ unsigned hipack(unsigned a, unsigned b) {
    return __builtin_amdgcn_perm(b, a, 0x07060302u);
}

// truncation split: hi = trunc-bf16(x), lo = trunc-bf16(x - hi)
__device__ __forceinline__ void cvt2(float x, float y, unsigned& h, unsigned& l) {
    unsigned ux = __float_as_uint(x), uy = __float_as_uint(y);
    h = hipack(ux, uy);
    float rx = x - __uint_as_float(ux & 0xFFFF0000u);
    float ry = y - __uint_as_float(uy & 0xFFFF0000u);
    l = hipack(__float_as_uint(rx), __float_as_uint(ry));
}

__device__ __forceinline__ void cvt8(const float4& f0, const float4& f1,
                                     uint4& hv, uint4& lv) {
    cvt2(f0.x, f0.y, hv.x, lv.x);
    cvt2(f0.z, f0.w, hv.y, lv.y);
    cvt2(f1.x, f1.y, hv.z, lv.z);
    cvt2(f1.z, f1.w, hv.w, lv.w);
}

__device__ __forceinline__ ushort f2bf(float x) {
    union { __hip_bfloat16 b; ushort u; } cv;
    cv.b = __float2bfloat16(x);
    return cv.u;
}

__device__ __forceinline__ void gld16(const void* g, void* l) {
    __builtin_amdgcn_global_load_lds((const __attribute__((address_space(1))) void*)g,
                                     (__attribute__((address_space(3))) void*)l,
                                     16, 0, 0);
}

// ---------------------------------------------------------------------------
// Fused convert: Wq/Wk/Wv -> truncation-split hi+lo (W-residual is the
// numerically-critical correlated term); x and Wo -> RNE bf16 hi-only
// (their residual terms average out: ~1e-5 contribution at the output).
// ---------------------------------------------------------------------------
__global__ __launch_bounds__(256) void convert_all(
    const float* __restrict__ x,
    const float* __restrict__ Wq, const float* __restrict__ Wk,
    const float* __restrict__ Wv, const float* __restrict__ Wo,
    ushort* __restrict__ Xhi,
    ushort* __restrict__ Whi, ushort* __restrict__ Wlo,
    ushort* __restrict__ Wohi)
{
    const int b = blockIdx.x;
    const float* src;
    ushort* hi;
    ushort* lo = nullptr;
    size_t off;
    if (b < 2048)      { src = x;  hi = Xhi;  off = (size_t)b * 2048; }
    else if (b < 2560) { src = Wq; hi = Whi;             lo = Wlo;             off = (size_t)(b - 2048) * 2048; }
    else if (b < 3072) { src = Wk; hi = Whi + (1 << 20); lo = Wlo + (1 << 20); off = (size_t)(b - 2560) * 2048; }
    else if (b < 3584) { src = Wv; hi = Whi + 2 * (1 << 20); lo = Wlo + 2 * (1 << 20); off = (size_t)(b - 3072) * 2048; }
    else               { src = Wo; hi = Wohi; off = (size_t)(b - 3584) * 2048; }

    const size_t i = off + (size_t)threadIdx.x * 8;
    const float4 f0 = *(const float4*)&src[i];
    const float4 f1 = *(const float4*)&src[i + 4];
    if (lo) {
        uint4 hv, lv;
        cvt8(f0, f1, hv, lv);
        *(uint4*)&hi[i] = hv;
        *(uint4*)&lo[i] = lv;
    } else {
        uint4 hv;
        hv.x = (unsigned)f2bf(f0.x) | ((unsigned)f2bf(f0.y) << 16);
        hv.y = (unsigned)f2bf(f0.z) | ((unsigned)f2bf(f0.w) << 16);
        hv.z = (unsigned)f2bf(f1.x) | ((unsigned)f2bf(f1.y) << 16);
        hv.w = (unsigned)f2bf(f1.z) | ((unsigned)f2bf(f1.w) << 16);
        *(uint4*)&hi[i] = hv;
    }
}

// ---------------------------------------------------------------------------
// Fused QKV GEMM: A = RNE-bf16 x (single plane), B = split W (hi+lo).
// 2 MFMAs per tile: ah*bh + ah*bl (x-residual term dropped — i.i.d. error,
// averages out; W-residual kept — correlated). Single-buffered pure-gld16,
// two-phase barrier (r9-proven). Per-iter LDS traffic 72KB vs r9's 96KB.
// ---------------------------------------------------------------------------
__global__ __launch_bounds__(256, 3) void qkv_gemm(
    const ushort* __restrict__ Xhi,
    const ushort* __restrict__ Whi, const ushort* __restrict__ Wlo,
    const float* __restrict__ bq, const float* __restrict__ bk,
    const float* __restrict__ bv,
    ushort* __restrict__ Qb, ushort* __restrict__ Kb, ushort* __restrict__ Vt)
{
    // K-loop: Ah[0..4095] Bh[4096..8191] Bl[8192..12287] (24KB)
    // epilogue reuse: 128 x 136 tile (17408 ushorts = 34KB) -> LDS block 34KB
    __shared__ __align__(16) ushort smem[17408];

    const int tid = threadIdx.x;
    const int wave = tid >> 6;
    const int lane = tid & 63;
    const int lm = lane & 15;
    const int lq = lane >> 4;
    const int wy = wave >> 1;
    const int wx = wave & 1;
    const int m0 = blockIdx.x * 128;
    const int nbase = blockIdx.y * 128;

    // staging map: thread t -> row r0 = t>>2 (and r0+64), LDS slot c = t&3,
    // global chunk g = c ^ swz(r0&15)
    const int c = tid & 3;
    const int r0 = tid >> 2;
    const int g = c ^ swz(r0 & 15);
    const ushort* gah = Xhi + (size_t)(m0 + r0) * DIMSZ + g * 8;
    const ushort* gbh = Whi + (size_t)(nbase + r0) * DIMSZ + g * 8;
    const ushort* gbl = Wlo + (size_t)(nbase + r0) * DIMSZ + g * 8;
    const int wofs = wave * 512;

    // frag read offsets
    const int fo = lm * 32 + (((lq ^ swz(lm)) & 3) << 3);
    int aofs[4], bofs[4];
#pragma unroll
    for (int i = 0; i < 4; ++i) {
        aofs[i] = (wy * 64 + i * 16) * 32 + fo;
        bofs[i] = (wx * 64 + i * 16) * 32 + fo;
    }

    f32x4 acc[4][4] = {};

    // stage k-tile 0
    {
        gld16(gah, smem + wofs);                 gld16(gah + 64 * DIMSZ, smem + 2048 + wofs);
        gld16(gbh, smem + 4096 + wofs);          gld16(gbh + 64 * DIMSZ, smem + 6144 + wofs);
        gld16(gbl, smem + 8192 + wofs);          gld16(gbl + 64 * DIMSZ, smem + 10240 + wofs);
    }

    for (int kk = 0; kk < 32; ++kk) {
        __syncthreads();   // barrier1: staging for tile kk landed (vmcnt drain)

        const ushort* Ah = smem;
        const ushort* Bh = smem + 4096;
        const ushort* Bl = smem + 8192;

        bf16x8 ahf[4], bhf[4], blf[4];
#pragma unroll
        for (int i = 0; i < 4; ++i) {
            ahf[i] = *(const bf16x8*)&Ah[aofs[i]];
            bhf[i] = *(const bf16x8*)&Bh[bofs[i]];
            blf[i] = *(const bf16x8*)&Bl[bofs[i]];
        }

        __syncthreads();   // barrier2: all frag reads done (lgkm only — cheap)

        if (kk + 1 < 32) {
            const int k0 = (kk + 1) * 32;
            gld16(gah + k0, smem + wofs);                 gld16(gah + 64 * DIMSZ + k0, smem + 2048 + wofs);
            gld16(gbh + k0, smem + 4096 + wofs);          gld16(gbh + 64 * DIMSZ + k0, smem + 6144 + wofs);
            gld16(gbl + k0, smem + 8192 + wofs);          gld16(gbl + 64 * DIMSZ + k0, smem + 10240 + wofs);
        }

#pragma unroll
        for (int i = 0; i < 4; ++i)
#pragma unroll
            for (int j = 0; j < 4; ++j) {
                acc[i][j] = __builtin_amdgcn_mfma_f32_16x16x32_bf16(ahf[i], bhf[j], acc[i][j], 0, 0, 0);
                acc[i][j] = __builtin_amdgcn_mfma_f32_16x16x32_bf16(ahf[i], blf[j], acc[i][j], 0, 0, 0);
            }
    }

    const int mat = blockIdx.y >> 3;      // 0:Q 1:K 2:V (block-uniform)
    const float* bias = (mat == 0) ? bq : (mat == 1) ? bk : bv;
    const int nloc0 = (blockIdx.y & 7) * 128;
    const int b = m0 >> 11;
    const int s0 = m0 & (SEQ - 1);
    ushort* sf = smem;                    // flat reuse (17408 ushorts)

    __syncthreads();   // K-loop traffic complete before smem reuse

    if (mat == 2) {
        // ---- V: transpose to [d][s], key-permuted within 32-blocks
#pragma unroll
        for (int j = 0; j < 4; ++j) {
            const int nc = nloc0 + wx * 64 + j * 16 + lm;
            const float bb = bias[nc];
            const int d = j * 16 + lm;
#pragma unroll
            for (int i = 0; i < 4; ++i) {
                // permuted position within 32-block: 8*lq + 4*(i&1) + rr
                const int ss = wy * 64 + (i >> 1) * 32 + lq * 8 + (i & 1) * 4;
                ushort4 pk;
                pk.x = f2bf(acc[i][j][0] + bb);
                pk.y = f2bf(acc[i][j][1] + bb);
                pk.z = f2bf(acc[i][j][2] + bb);
                pk.w = f2bf(acc[i][j][3] + bb);
                *(ushort4*)&sf[(wx * 64 + d) * 136 + ss] = pk;
            }
        }
        __syncthreads();
#pragma unroll
        for (int p = 0; p < 8; ++p) {
            const int idx = p * 256 + tid;
            const int row = idx >> 4;          // hh*64 + d
            const int hh = row >> 6;
            const int d = row & 63;
            const int sseg = (idx & 15) * 8;
            const uint4 v = *(const uint4*)&sf[row * 136 + sseg];
            const int hg = (nloc0 >> 6) + hh;
            *(uint4*)&Vt[((size_t)(b * NHEAD + hg) * HDIM + d) * SEQ + s0 + sseg] = v;
        }
    } else {
        // ---- Q/K: [s][d] tile in LDS, uint4 coalesced out
        ushort* dst = (mat == 0) ? Qb : Kb;
        const float sc = (mat == 0) ? QSCALE : 1.0f;
#pragma unroll
        for (int j = 0; j < 4; ++j) {
            const int col = wx * 64 + j * 16 + lm;      // 0..127
            const float bb = bias[nloc0 + col];
#pragma unroll
            for (int i = 0; i < 4; ++i) {
                const int rbase = wy * 64 + i * 16 + lq * 4;
#pragma unroll
                for (int rr = 0; rr < 4; ++rr)
                    sf[(rbase + rr) * 136 + col] = f2bf((acc[i][j][rr] + bb) * sc);
            }
        }
        __syncthreads();
#pragma unroll
        for (int p = 0; p < 8; ++p) {
            const int idx = p * 256 + tid;
            const int row = idx >> 4;          // local s: 0..127
            const int seg = idx & 15;          // 8-col segment
            const uint4 v = *(const uint4*)&sf[row * 136 + seg * 8];
            const int nc0 = nloc0 + seg * 8;
            const int h = nc0 >> 6;
            const int d = nc0 & 63;
            *(uint4*)&dst[((size_t)(b * NHEAD + h) * SEQ + s0 + row) * HDIM + d] = v;
        }
    }
}

// ---------------------------------------------------------------------------
// MFMA flash attention, S^T formulation. CTX out = single bf16 plane (RNE);
// plain-bf16 oproj error contribution ~2e-5 (out values are small).
// ---------------------------------------------------------------------------
__global__ __launch_bounds__(256) void flash_attn_mfma(
    const ushort* __restrict__ Qb, const ushort* __restrict__ Kb,
    const ushort* __restrict__ Vt, ushort* __restrict__ CTXhi)
{
    __shared__ __align__(16) ushort Ks[2][4096];
    __shared__ __align__(16) ushort Vs[2][4096];

    const int tid = threadIdx.x;
    const int w = tid >> 6;
    const int l = tid & 63;
    const int lm = l & 15;
    const int lq = l >> 4;
    const int q0 = blockIdx.x * 128;
    const int bh = blockIdx.y;

    const ushort* Kg = Kb + (size_t)bh * SEQ * HDIM;
    const ushort* Vg = Vt + (size_t)bh * HDIM * SEQ;

    const int srow = w * 8 + (l >> 3);
    const int sc_ = (l & 7) ^ ((l >> 3) & 7);

    bf16x8 qf[2][2];
#pragma unroll
    for (int rt = 0; rt < 2; ++rt)
#pragma unroll
        for (int kt = 0; kt < 2; ++kt)
            qf[rt][kt] = *(const bf16x8*)&Qb[((size_t)bh * SEQ + q0 + w * 32 + rt * 16 + lm) * HDIM + kt * 32 + lq * 8];

    int koff[4][2];
#pragma unroll
    for (int t = 0; t < 4; ++t)
#pragma unroll
        for (int kt = 0; kt < 2; ++kt)
            koff[t][kt] = (t * 16 + lm) * 64 + (((kt * 4 + lq) ^ (lm & 7)) << 3);

    f32x4 o[2][4] = {};
    float l_[2] = {0.0f, 0.0f};

    {
        ushort* kb = &Ks[0][0];
        ushort* vb = &Vs[0][0];
#pragma unroll
        for (int p = 0; p < 2; ++p) {
            const int row = p * 32 + srow;
            gld16(Kg + (size_t)row * HDIM + sc_ * 8, kb + (p * 32 + w * 8) * 64);
            gld16(Vg + (size_t)row * SEQ + sc_ * 8, vb + (p * 32 + w * 8) * 64);
        }
    }

    for (int ch = 0; ch < SEQ / 64; ++ch) {
        __syncthreads();

        if (ch + 1 < SEQ / 64) {
            const int kc = (ch + 1) * 64;
            ushort* kb = &Ks[(ch + 1) & 1][0];
            ushort* vb = &Vs[(ch + 1) & 1][0];
#pragma unroll
            for (int p = 0; p < 2; ++p) {
                const int row = p * 32 + srow;
                gld16(Kg + (size_t)(kc + row) * HDIM + sc_ * 8, kb + (p * 32 + w * 8) * 64);
                gld16(Vg + (size_t)row * SEQ + kc + sc_ * 8, vb + (p * 32 + w * 8) * 64);
            }
        }

        const ushort* kb = &Ks[ch & 1][0];
        const ushort* vb = &Vs[ch & 1][0];

        f32x4 st[2][4] = {};
#pragma unroll
        for (int ct = 0; ct < 4; ++ct)
#pragma unroll
            for (int kt = 0; kt < 2; ++kt) {
                const bf16x8 kf = *(const bf16x8*)&kb[koff[ct][kt]];
#pragma unroll
                for (int rt = 0; rt < 2; ++rt)
                    st[rt][ct] = __builtin_amdgcn_mfma_f32_16x16x32_bf16(kf, qf[rt][kt], st[rt][ct], 0, 0, 0);
            }

#pragma unroll
        for (int rt = 0; rt < 2; ++rt) {
            float ls = 0.0f;
#pragma unroll
            for (int ct = 0; ct < 4; ++ct)
#pragma unroll
                for (int r = 0; r < 4; ++r) {
                    const float p = __builtin_amdgcn_exp2f(st[rt][ct][r]);
                    st[rt][ct][r] = p;
                    ls += p;
                }
            ls += __shfl_xor(ls, 16, 64);
            ls += __shfl_xor(ls, 32, 64);
            l_[rt] += ls;
        }

        bf16x8 pf[2][2];
#pragma unroll
        for (int rt = 0; rt < 2; ++rt)
#pragma unroll
            for (int kt2 = 0; kt2 < 2; ++kt2) {
                union { bf16x8 v; ushort u[8]; } pk;
#pragma unroll
                for (int t = 0; t < 2; ++t)
#pragma unroll
                    for (int r = 0; r < 4; ++r)
                        pk.u[t * 4 + r] = f2bf(st[rt][kt2 * 2 + t][r]);
                pf[rt][kt2] = pk.v;
            }

#pragma unroll
        for (int dt = 0; dt < 4; ++dt)
#pragma unroll
            for (int kt2 = 0; kt2 < 2; ++kt2) {
                const bf16x8 vf = *(const bf16x8*)&vb[koff[dt][kt2]];
#pragma unroll
                for (int rt = 0; rt < 2; ++rt)
                    o[rt][dt] = __builtin_amdgcn_mfma_f32_16x16x32_bf16(pf[rt][kt2], vf, o[rt][dt], 0, 0, 0);
            }
    }

    const int b = bh >> 4;
    const int h = bh & 15;
#pragma unroll
    for (int rt = 0; rt < 2; ++rt) {
        const float linv_me = 1.0f / l_[rt];
#pragma unroll
        for (int r = 0; r < 4; ++r) {
            const float lr = __shfl(linv_me, lq * 4 + r, 64);
            const int srow_ = q0 + w * 32 + rt * 16 + lq * 4 + r;
            const size_t base = ((size_t)b * SEQ + srow_) * DIMSZ + h * HDIM;
#pragma unroll
            for (int dt = 0; dt < 4; ++dt)
                CTXhi[base + dt * 16 + lm] = f2bf(o[rt][dt][r] * lr);
        }
    }
}

// ---------------------------------------------------------------------------
// Output projection: PLAIN bf16 (CTXhi x Wohi, 1 MFMA/tile). Single-buffer
// two-phase-barrier pure-gld16 (r9 structure). 64x128 tiles, 512 blocks,
// 12KB LDS.
// ---------------------------------------------------------------------------
__global__ __launch_bounds__(256) void oproj_gemm(
    const ushort* __restrict__ Ahi_g, const ushort* __restrict__ Bhi_g,
    const float* __restrict__ bias, float* __restrict__ out)
{
    __shared__ __align__(16) ushort smem[6144];   // Ah[2048] Bh[4096] = 12KB

    const int tid = threadIdx.x;
    const int wave = tid >> 6;
    const int lane = tid & 63;
    const int lm = lane & 15;
    const int lq = lane >> 4;
    const int wy = wave >> 1;
    const int wx = wave & 1;
    const int m0 = blockIdx.x * 64;
    const int n0 = blockIdx.y * 128;

    const int c = tid & 3;
    const int r0 = tid >> 2;
    const int g = c ^ swz(r0 & 15);
    const ushort* gah = Ahi_g + (size_t)(m0 + r0) * DIMSZ + g * 8;
    const ushort* gbh = Bhi_g + (size_t)(n0 + r0) * DIMSZ + g * 8;
    const int wofs = wave * 512;

    const int fo = lm * 32 + (((lq ^ swz(lm)) & 3) << 3);
    int aofs[2], bofs[4];
#pragma unroll
    for (int i = 0; i < 2; ++i) aofs[i] = (wy * 32 + i * 16) * 32 + fo;
#pragma unroll
    for (int j = 0; j < 4; ++j) bofs[j] = (wx * 64 + j * 16) * 32 + fo;

    f32x4 acc[2][4] = {};

    {
        gld16(gah, smem + wofs);
        gld16(gbh, smem + 2048 + wofs);   gld16(gbh + 64 * DIMSZ, smem + 4096 + wofs);
    }

    for (int kk = 0; kk < 32; ++kk) {
        __syncthreads();   // staged

        bf16x8 ahf[2], bhf[4];
#pragma unroll
        for (int i = 0; i < 2; ++i) ahf[i] = *(const bf16x8*)&smem[aofs[i]];
#pragma unroll
        for (int j = 0; j < 4; ++j) bhf[j] = *(const bf16x8*)&smem[2048 + bofs[j]];

        __syncthreads();   // reads done

        if (kk + 1 < 32) {
            const int k0 = (kk + 1) * 32;
            gld16(gah + k0, smem + wofs);
            gld16(gbh + k0, smem + 2048 + wofs);   gld16(gbh + 64 * DIMSZ + k0, smem + 4096 + wofs);
        }

#pragma unroll
        for (int i = 0; i < 2; ++i)
#pragma unroll
            for (int j = 0; j < 4; ++j)
                acc[i][j] = __builtin_amdgcn_mfma_f32_16x16x32_bf16(ahf[i], bhf[j], acc[i][j], 0, 0, 0);
    }

#pragma unroll
    for (int j = 0; j < 4; ++j) {
        const int nc = n0 + wx * 64 + j * 16 + lm;
        const float bb = bias[nc];
#pragma unroll
        for (int i = 0; i < 2; ++i) {
            const int mb = m0 + wy * 32 + i * 16 + lq * 4;
#pragma unroll
            for (int rr = 0; rr < 4; ++rr)
                out[(size_t)(mb + rr) * DIMSZ + nc] = acc[i][j][rr] + bb;
        }
    }
}

// ---------------------------------------------------------------------------
extern "C" void kernel_launch(void* const* d_in, const int* in_sizes, int n_in,
                              void* d_out, int out_size, void* d_ws, size_t ws_size,
                              hipStream_t stream)
{
    const float* x  = (const float*)d_in[0];
    const float* Wq = (const float*)d_in[1];
    const float* bq = (const float*)d_in[2];
    const float* Wk = (const float*)d_in[3];
    const float* bk = (const float*)d_in[4];
    const float* Wv = (const float*)d_in[5];
    const float* bv = (const float*)d_in[6];
    const float* Wo = (const float*)d_in[7];
    const float* bo = (const float*)d_in[8];
    float* out = (float*)d_out;

    const size_t elems = (size_t)NROWS * DIMSZ;   // 4M
    ushort* Qb    = (ushort*)d_ws;                // 8MB
    ushort* Kb    = Qb + elems;                   // 8MB
    ushort* Vt    = Kb + elems;                   // 8MB
    ushort* CTXhi = Vt + elems;                   // 8MB (overlay: Xhi)
    ushort* Whi   = CTXhi + elems;                // 6MB
    ushort* Wlo   = Whi + 3 * (1 << 20);          // 6MB
    ushort* Wohi  = Wlo + 3 * (1 << 20);          // 2MB  (peak 46MB)
    ushort* Xhi   = CTXhi;                        // dead before flash writes CTX

    convert_all<<<4096, 256, 0, stream>>>(x, Wq, Wk, Wv, Wo,
                                          Xhi, Whi, Wlo, Wohi);

    qkv_gemm<<<dim3(32, 24), 256, 0, stream>>>(Xhi, Whi, Wlo, bq, bk, bv, Qb, Kb, Vt);

    flash_attn_mfma<<<dim3(SEQ / 128, BATCH * NHEAD), 256, 0, stream>>>(Qb, Kb, Vt, CTXhi);

    oproj_gemm<<<dim3(64, 8), 256, 0, stream>>>(CTXhi, Wohi, bo, out);
}